// Round 1
// baseline (9528.288 us; speedup 1.0000x reference)
//
#include <hip/hip_runtime.h>
#include <stdint.h>

#define T 4096
#define S 256
#define NBLK 256   // one block per DP row
#define BTHR 64    // one wave per block

#define POISON 0xAAAAAAAAu

__device__ __forceinline__ uint32_t aload(const uint32_t* p) {
  return __hip_atomic_load(p, __ATOMIC_RELAXED, __HIP_MEMORY_SCOPE_AGENT);
}
__device__ __forceinline__ void astore(uint32_t* p, uint32_t v) {
  __hip_atomic_store(p, v, __ATOMIC_RELAXED, __HIP_MEMORY_SCOPE_AGENT);
}

// Simple one-shot grid barrier (separate cnt/gen pair per call site, zeroed by
// hipMemsetAsync before launch). All NBLK blocks are co-resident (256 tiny
// 1-wave blocks on 256 CUs), so spinning is safe.
__device__ __forceinline__ void gbar(unsigned* cnt, unsigned* gen, unsigned nb) {
  __syncthreads();
  if (threadIdx.x == 0) {
    __threadfence();  // agent-scope release of prior plain writes (bp, H, ...)
    unsigned old = __hip_atomic_fetch_add(cnt, 1u, __ATOMIC_ACQ_REL, __HIP_MEMORY_SCOPE_AGENT);
    if (old == nb - 1u) {
      __hip_atomic_store(gen, 1u, __ATOMIC_RELEASE, __HIP_MEMORY_SCOPE_AGENT);
    } else {
      while (__hip_atomic_load(gen, __ATOMIC_ACQUIRE, __HIP_MEMORY_SCOPE_AGENT) == 0u) {
        __builtin_amdgcn_s_sleep(8);
      }
    }
    __threadfence();  // acquire side: invalidate stale cached lines
  }
  __syncthreads();
}

__global__ __launch_bounds__(BTHR, 1) void viterbi_kernel(
    const float* __restrict__ pot, float* __restrict__ out,
    uint8_t* __restrict__ bp, int* __restrict__ H, int* __restrict__ bstate,
    unsigned* __restrict__ ctrl) {
  const int b = blockIdx.x;
  const int lane = threadIdx.x;
  float* vout = out + T;                    // v region: (T,S) floats
  uint32_t* vout_u = (uint32_t*)vout;
  const float4* pot4 = (const float4*)pot;  // pot[t][s][4k..4k+3]

  // ---- init: block 0 publishes v[0] = potentials[0,0,:]
  if (b == 0) {
    float4 p0 = pot4[lane];  // (t=0, s=0) row, elements 4*lane..
    astore(vout_u + 4 * lane + 0, __float_as_uint(p0.x));
    astore(vout_u + 4 * lane + 1, __float_as_uint(p0.y));
    astore(vout_u + 4 * lane + 2, __float_as_uint(p0.z));
    astore(vout_u + 4 * lane + 3, __float_as_uint(p0.w));
  }

  // ---- forward DP: block b owns row s = b for every t
  const int s = b;
  float4 P = pot4[((size_t)1 * S + s) * (S / 4) + lane];  // pot[1][s][4l..]
  for (int t = 1; t < T; ++t) {
    // Poll v[t-1][4l..4l+3] (data doubles as the ready flag: != poison).
    const uint32_t* vp = vout_u + (size_t)(t - 1) * S + 4 * lane;
    uint32_t a0, a1, a2, a3;
    for (;;) {
      a0 = aload(vp + 0); a1 = aload(vp + 1);
      a2 = aload(vp + 2); a3 = aload(vp + 3);
      if (a0 != POISON && a1 != POISON && a2 != POISON && a3 != POISON) break;
    }
    // Prefetch next step's pot row; flies during compute+store+next poll.
    float4 Pn = P;
    if (t + 1 < T) Pn = pot4[((size_t)(t + 1) * S + s) * (S / 4) + lane];

    float v0 = __uint_as_float(a0), v1 = __uint_as_float(a1),
          v2 = __uint_as_float(a2), v3 = __uint_as_float(a3);
    float s0 = v0 + P.x, s1 = v1 + P.y, s2 = v2 + P.z, s3 = v3 + P.w;

    // first-index argmax (matches np/jnp argmax tie rule)
    float m = s0; int idx = 4 * lane;
    if (s1 > m) { m = s1; idx = 4 * lane + 1; }
    if (s2 > m) { m = s2; idx = 4 * lane + 2; }
    if (s3 > m) { m = s3; idx = 4 * lane + 3; }
#pragma unroll
    for (int off = 1; off < 64; off <<= 1) {
      float om = __shfl_xor(m, off, 64);
      int   oi = __shfl_xor(idx, off, 64);
      if (om > m || (om == m && oi < idx)) { m = om; idx = oi; }
    }
    // logsumexp with max subtraction (gamma = 1)
    float e = __expf(s0 - m) + __expf(s1 - m) + __expf(s2 - m) + __expf(s3 - m);
#pragma unroll
    for (int off = 1; off < 64; off <<= 1) e += __shfl_xor(e, off, 64);

    if (lane == 0) {
      float vt = m + __logf(e);
      astore(vout_u + (size_t)t * S + s, __float_as_uint(vt));
      bp[(size_t)t * S + s] = (uint8_t)idx;  // read only after gbar
    }
    P = Pn;
  }

  gbar(ctrl + 0, ctrl + 1, NBLK);

  // ---- phase 1: per-chunk backpointer composition H_c (chunk len 64)
  // H[c][e] = state at time tau_{c-1} given state e at tau_c, tau_c = c*64+63.
  {
    int g = b * BTHR + lane;  // 0..16383
    int c = 1 + (g >> 8);
    if (c <= 63) {
      int e = g & 255;
      int st = e;
      for (int t = c * 64 + 63; t >= c * 64; --t) st = bp[(size_t)t * S + st];
      H[c * 256 + e] = st;
    }
  }

  gbar(ctrl + 2, ctrl + 3, NBLK);

  // ---- phase 2: block 0: first-index argmax of v[T-1], then boundary walk
  if (b == 0) {
    const float* vlast = vout + (size_t)(T - 1) * S;
    float m = vlast[lane]; int idx = lane;
#pragma unroll
    for (int k = 1; k < 4; ++k) {
      float x = vlast[lane + 64 * k];
      if (x > m) { m = x; idx = lane + 64 * k; }
    }
#pragma unroll
    for (int off = 1; off < 64; off <<= 1) {
      float om = __shfl_xor(m, off, 64);
      int   oi = __shfl_xor(idx, off, 64);
      if (om > m || (om == m && oi < idx)) { m = om; idx = oi; }
    }
    if (lane == 0) {
      int st = idx;
      bstate[63] = st;
      for (int c = 63; c >= 1; --c) { st = H[c * 256 + st]; bstate[c - 1] = st; }
    }
  }

  gbar(ctrl + 4, ctrl + 5, NBLK);

  // ---- phase 3: blocks 0..63 emit path entries for chunk c = b
  if (b < 64 && lane == 0) {
    int c = b;
    int st = bstate[c];
    int tau = c * 64 + 63;
    int lo = (c == 0) ? 0 : c * 64;
    out[tau] = (float)st;
    for (int t = tau; t >= lo + 1; --t) {
      st = bp[(size_t)t * S + st];
      out[t - 1] = (float)st;
    }
  }
}

extern "C" void kernel_launch(void* const* d_in, const int* in_sizes, int n_in,
                              void* d_out, int out_size, void* d_ws, size_t ws_size,
                              hipStream_t stream) {
  const float* pot = (const float*)d_in[0];
  float* out = (float*)d_out;

  char* wsb = (char*)d_ws;
  unsigned* ctrl = (unsigned*)wsb;                                   // 6 uints (64 B reserved)
  uint8_t* bp = (uint8_t*)(wsb + 64);                                // T*S bytes = 1 MB
  int* H = (int*)(wsb + 64 + (size_t)T * S);                         // 64*256 ints
  int* bstate = (int*)(wsb + 64 + (size_t)T * S + 64 * 256 * 4);     // 64 ints

  // Zero barrier state; poison the v region so value!=poison is the ready flag.
  // (Harness memsets d_out to 0 before the correctness call and 0xAA before
  // timed replays — we must not rely on either, so poison it ourselves.)
  hipMemsetAsync(ctrl, 0, 64, stream);
  hipMemsetAsync(out + T, 0xAA, (size_t)T * S * sizeof(float), stream);

  viterbi_kernel<<<NBLK, BTHR, 0, stream>>>(pot, out, bp, H, bstate, ctrl);
}